// Round 1
// baseline (209.412 us; speedup 1.0000x reference)
//
#include <hip/hip_runtime.h>
#include <hip/hip_bf16.h>
#include <math.h>

// Problem constants
#define B_  64
#define L_  512
#define D_  768
#define K_  6      // NUM_LABELS
#define P_  3      // POL_DIM

// ws layout: srcidx[B*L] ints (131072 B), then WT[K][D] floats (18432 B)
#define WS_SRCIDX_BYTES (B_ * L_ * 4)

// ---------------------------------------------------------------------------
// k1: per-batch inclusive scan of valid_ids -> srcidx[b][j] = l of j-th valid
//     token, -1 if j >= nvalid. Also: transpose W_cls -> WT[6][768] (block 1),
//     seed apc output region with b_apc (block 0).
// ---------------------------------------------------------------------------
__global__ __launch_bounds__(512) void k1_prefix(
    const int* __restrict__ valid, const float* __restrict__ w_cls,
    const float* __restrict__ b_apc, int* __restrict__ srcidx,
    float* __restrict__ wt, float* __restrict__ out_apc) {
  __shared__ int s[L_];
  const int b = blockIdx.x;
  const int l = threadIdx.x;

  const int v = valid[b * L_ + l];
  s[l] = v;
  __syncthreads();
  // Hillis-Steele inclusive scan over 512 entries
  for (int off = 1; off < L_; off <<= 1) {
    int add = (l >= off) ? s[l - off] : 0;
    __syncthreads();
    s[l] += add;
    __syncthreads();
  }
  const int pos = s[l] - 1;  // rank among valids (if v==1)

  srcidx[b * L_ + l] = -1;
  __syncthreads();
  if (v) srcidx[b * L_ + pos] = l;

  // Side jobs (wave-cheap, hidden under the 64-block launch):
  if (b == 0 && l < B_ * P_) out_apc[l] = b_apc[l % P_];
  if (b == 1) {
    for (int i = l; i < K_ * D_; i += L_) {
      int k = i / D_, d = i - k * D_;
      wt[k * D_ + d] = w_cls[d * K_ + k];
    }
  }
}

// ---------------------------------------------------------------------------
// k2: ATE logits. One wave per output row (b, j). 32768 rows total.
//   row valid  -> gather x[b, srcidx[row]], dot with WT (L1-resident), + b_cls
//   row invalid-> write b_cls
// ---------------------------------------------------------------------------
__global__ __launch_bounds__(256) void k2_ate(
    const float* __restrict__ x, const float* __restrict__ wt,
    const float* __restrict__ b_cls, const int* __restrict__ srcidx,
    float* __restrict__ out) {
  const int wid = threadIdx.x >> 6;
  const int lane = threadIdx.x & 63;
  const int row = blockIdx.x * 4 + wid;  // 0..32767
  const int src = srcidx[row];           // wave-uniform
  float* o = out + (size_t)row * K_;

  if (src < 0) {
    if (lane < K_) o[lane] = b_cls[lane];
    return;
  }

  const int b = row >> 9;
  const float4* x4 = (const float4*)(x + ((size_t)(b * L_ + src)) * D_);

  float acc[K_] = {0.f, 0.f, 0.f, 0.f, 0.f, 0.f};
#pragma unroll
  for (int c = 0; c < 3; ++c) {
    const float4 xv = x4[lane + 64 * c];  // coalesced 16B/lane
#pragma unroll
    for (int k = 0; k < K_; ++k) {
      const float4 wv = ((const float4*)(wt + k * D_))[lane + 64 * c];
      acc[k] += xv.x * wv.x + xv.y * wv.y + xv.z * wv.z + xv.w * wv.w;
    }
  }
  // 64-lane butterfly reduction of 6 partials
#pragma unroll
  for (int k = 0; k < K_; ++k) {
#pragma unroll
    for (int off = 32; off >= 1; off >>= 1) acc[k] += __shfl_xor(acc[k], off, 64);
  }
  if (lane == 0) {
#pragma unroll
    for (int k = 0; k < K_; ++k) o[k] = acc[k] + b_cls[k];
  }
}

// ---------------------------------------------------------------------------
// k3: Pooler + APC head. Thread = (b, j): b wave-uniform, j = lane-coalesced.
// Grid: 16 b-groups x 12 j-groups = 192 blocks of 256 (4 waves = 4 b's).
// pooled value stays in a register; apc contracted via wave-reduce + atomics.
// ---------------------------------------------------------------------------
__global__ __launch_bounds__(256) void k3_pool(
    const float* __restrict__ x, const float* __restrict__ w_pool,
    const float* __restrict__ b_pool, const float* __restrict__ w_apc,
    const int* __restrict__ srcidx, float* __restrict__ out_apc) {
  const int wid = threadIdx.x >> 6;
  const int lane = threadIdx.x & 63;
  const int bg = blockIdx.x & 15;   // 16 b-groups
  const int jg = blockIdx.x >> 4;   // 12 j-groups
  const int b = bg * 4 + wid;       // wave-uniform batch
  const int j = jg * 64 + lane;     // lane-coalesced output dim

  const int src = srcidx[b * L_];   // first-valid token l, or -1
  float acc = 0.f;
  if (src >= 0) {
    const float4* x4 = (const float4*)(x + ((size_t)(b * L_ + src)) * D_);
    const float* wb = w_pool + j;
#pragma unroll 4
    for (int i = 0; i < D_ / 4; ++i) {
      const float4 xv = x4[i];  // wave-uniform broadcast load
      const float* w = wb + (size_t)(4 * i) * D_;
      acc += xv.x * w[0] + xv.y * w[D_] + xv.z * w[2 * D_] + xv.w * w[3 * D_];
    }
  }
  const float val = tanhf(acc + b_pool[j]);

  float p0 = val * w_apc[j * P_ + 0];
  float p1 = val * w_apc[j * P_ + 1];
  float p2 = val * w_apc[j * P_ + 2];
#pragma unroll
  for (int off = 32; off >= 1; off >>= 1) {
    p0 += __shfl_xor(p0, off, 64);
    p1 += __shfl_xor(p1, off, 64);
    p2 += __shfl_xor(p2, off, 64);
  }
  if (lane == 0) {
    atomicAdd(out_apc + b * P_ + 0, p0);
    atomicAdd(out_apc + b * P_ + 1, p1);
    atomicAdd(out_apc + b * P_ + 2, p2);
  }
}

// ---------------------------------------------------------------------------
extern "C" void kernel_launch(void* const* d_in, const int* in_sizes, int n_in,
                              void* d_out, int out_size, void* d_ws, size_t ws_size,
                              hipStream_t stream) {
  const float* x      = (const float*)d_in[0];  // [B,L,D]
  const int*   valid  = (const int*)d_in[1];    // [B,L]
  const float* w_cls  = (const float*)d_in[2];  // [D,K]
  const float* b_cls  = (const float*)d_in[3];  // [K]
  const float* w_pool = (const float*)d_in[4];  // [D,D]
  const float* b_pool = (const float*)d_in[5];  // [D]
  const float* w_apc  = (const float*)d_in[6];  // [D,P]
  const float* b_apc  = (const float*)d_in[7];  // [P]

  float* out     = (float*)d_out;
  float* out_apc = out + (size_t)B_ * L_ * K_;  // apc region after ate logits

  int*   srcidx = (int*)d_ws;
  float* wt     = (float*)((char*)d_ws + WS_SRCIDX_BYTES);

  k1_prefix<<<B_, L_, 0, stream>>>(valid, w_cls, b_apc, srcidx, wt, out_apc);
  k2_ate<<<(B_ * L_) / 4, 256, 0, stream>>>(x, wt, b_cls, srcidx, out);
  k3_pool<<<192, 256, 0, stream>>>(x, w_pool, b_pool, w_apc, srcidx, out_apc);
}

// Round 2
// 192.458 us; speedup vs baseline: 1.0881x; 1.0881x over previous
//
#include <hip/hip_runtime.h>
#include <hip/hip_bf16.h>
#include <math.h>

// Problem constants
#define B_  64
#define L_  512
#define D_  768
#define K_  6      // NUM_LABELS
#define P_  3      // POL_DIM

#define WS_SRCIDX_BYTES (B_ * L_ * 4)

#define POOL_BLOCKS 192            // 16 b-groups x 12 j-groups (k3 role)
#define ATE_BLOCKS  4096           // 32768 rows / (4 waves x 2 rows)

typedef float f4_t __attribute__((ext_vector_type(4)));

// ---------------------------------------------------------------------------
// k1: per-batch inclusive scan of valid_ids -> srcidx[b][j] = l of j-th valid
//     token, -1 if j >= nvalid. Side jobs: transpose W_cls -> WT[6][768]
//     (block 1), seed apc output region with b_apc (block 0).
// ---------------------------------------------------------------------------
__global__ __launch_bounds__(512) void k1_prefix(
    const int* __restrict__ valid, const float* __restrict__ w_cls,
    const float* __restrict__ b_apc, int* __restrict__ srcidx,
    float* __restrict__ wt, float* __restrict__ out_apc) {
  __shared__ int s[L_];
  const int b = blockIdx.x;
  const int l = threadIdx.x;

  const int v = valid[b * L_ + l];
  s[l] = v;
  __syncthreads();
  for (int off = 1; off < L_; off <<= 1) {   // Hillis-Steele inclusive scan
    int add = (l >= off) ? s[l - off] : 0;
    __syncthreads();
    s[l] += add;
    __syncthreads();
  }
  const int pos = s[l] - 1;

  srcidx[b * L_ + l] = -1;
  __syncthreads();
  if (v) srcidx[b * L_ + pos] = l;

  if (b == 0 && l < B_ * P_) out_apc[l] = b_apc[l % P_];
  if (b == 1) {
    for (int i = l; i < K_ * D_; i += L_) {
      int k = i / D_, d = i - k * D_;
      wt[k * D_ + d] = w_cls[d * K_ + k];
    }
  }
}

// select a[i] from a fully-register-resident 6-array without dynamic indexing
__device__ __forceinline__ float sel6(const float a[K_], int i) {
  float r = a[0];
  r = (i == 1) ? a[1] : r;
  r = (i == 2) ? a[2] : r;
  r = (i == 3) ? a[3] : r;
  r = (i == 4) ? a[4] : r;
  r = (i == 5) ? a[5] : r;
  return r;
}

// ---------------------------------------------------------------------------
// Fused kernel. blockIdx < POOL_BLOCKS  -> pooler+APC role (overlaps ATE).
//               blockIdx >= POOL_BLOCKS -> ATE role: 2 rows/wave, wt in LDS,
//               nontemporal x stream, one contiguous 12-float store per wave.
// ---------------------------------------------------------------------------
__global__ __launch_bounds__(256) void k2_fused(
    const float* __restrict__ x, const float* __restrict__ wt,
    const float* __restrict__ b_cls, const int* __restrict__ srcidx,
    const float* __restrict__ w_pool, const float* __restrict__ b_pool,
    const float* __restrict__ w_apc, float* __restrict__ out,
    float* __restrict__ out_apc) {
  const int wid = threadIdx.x >> 6;
  const int lane = threadIdx.x & 63;

  if (blockIdx.x < POOL_BLOCKS) {
    // ---- pooler + APC head: b wave-uniform, j lane-coalesced ----
    const int bg = blockIdx.x & 15;
    const int jg = blockIdx.x >> 4;
    const int b = bg * 4 + wid;
    const int j = jg * 64 + lane;

    const int src = srcidx[b * L_];
    float acc = 0.f;
    if (src >= 0) {
      const float4* x4 = (const float4*)(x + ((size_t)(b * L_ + src)) * D_);
      const float* wb = w_pool + j;
#pragma unroll 4
      for (int i = 0; i < D_ / 4; ++i) {
        const float4 xv = x4[i];  // wave-uniform broadcast load
        const float* w = wb + (size_t)(4 * i) * D_;
        acc += xv.x * w[0] + xv.y * w[D_] + xv.z * w[2 * D_] + xv.w * w[3 * D_];
      }
    }
    const float val = tanhf(acc + b_pool[j]);

    float p0 = val * w_apc[j * P_ + 0];
    float p1 = val * w_apc[j * P_ + 1];
    float p2 = val * w_apc[j * P_ + 2];
#pragma unroll
    for (int off = 32; off >= 1; off >>= 1) {
      p0 += __shfl_xor(p0, off, 64);
      p1 += __shfl_xor(p1, off, 64);
      p2 += __shfl_xor(p2, off, 64);
    }
    if (lane == 0) {
      atomicAdd(out_apc + b * P_ + 0, p0);
      atomicAdd(out_apc + b * P_ + 1, p1);
      atomicAdd(out_apc + b * P_ + 2, p2);
    }
    return;
  }

  // ---- ATE role ----
  __shared__ f4_t swt[K_ * (D_ / 4)];  // 18 KB: WT[6][768] as float4
  for (int i = threadIdx.x; i < K_ * (D_ / 4); i += 256)
    swt[i] = ((const f4_t*)wt)[i];
  __syncthreads();

  const int ab = blockIdx.x - POOL_BLOCKS;
  const int row0 = ab * 8 + wid * 2;        // 2 consecutive rows, same batch
  const int src0 = srcidx[row0];            // wave-uniform
  const int src1 = srcidx[row0 + 1];        // wave-uniform
  const int b = row0 >> 9;

  float a0[K_] = {0.f, 0.f, 0.f, 0.f, 0.f, 0.f};
  float a1[K_] = {0.f, 0.f, 0.f, 0.f, 0.f, 0.f};

  if (src0 >= 0) {
    // invalid rows are a suffix per batch: src1<0 => reuse src0's row (L1 hit,
    // result discarded at store)
    const int s1 = (src1 >= 0) ? src1 : src0;
    const f4_t* x0 = (const f4_t*)(x + ((size_t)(b * L_ + src0)) * D_);
    const f4_t* x1 = (const f4_t*)(x + ((size_t)(b * L_ + s1)) * D_);
#pragma unroll
    for (int c = 0; c < 3; ++c) {
      const f4_t xv0 = __builtin_nontemporal_load(&x0[lane + 64 * c]);
      const f4_t xv1 = __builtin_nontemporal_load(&x1[lane + 64 * c]);
#pragma unroll
      for (int k = 0; k < K_; ++k) {
        const f4_t wv = swt[k * (D_ / 4) + lane + 64 * c];
        a0[k] += xv0.x * wv.x + xv0.y * wv.y + xv0.z * wv.z + xv0.w * wv.w;
        a1[k] += xv1.x * wv.x + xv1.y * wv.y + xv1.z * wv.z + xv1.w * wv.w;
      }
    }
#pragma unroll
    for (int k = 0; k < K_; ++k) {
#pragma unroll
      for (int off = 32; off >= 1; off >>= 1) {
        a0[k] += __shfl_xor(a0[k], off, 64);
        a1[k] += __shfl_xor(a1[k], off, 64);
      }
    }
  }

  // rows 2r,2r+1 are contiguous: lanes 0..11 store 12 contiguous floats
  if (lane < 12) {
    const int idx = (lane < 6) ? lane : lane - 6;
    float s;
    if (lane < 6) s = (src0 >= 0) ? sel6(a0, idx) : 0.f;
    else          s = (src1 >= 0) ? sel6(a1, idx) : 0.f;
    out[(size_t)row0 * K_ + lane] = s + b_cls[idx];
  }
}

// ---------------------------------------------------------------------------
extern "C" void kernel_launch(void* const* d_in, const int* in_sizes, int n_in,
                              void* d_out, int out_size, void* d_ws, size_t ws_size,
                              hipStream_t stream) {
  const float* x      = (const float*)d_in[0];  // [B,L,D]
  const int*   valid  = (const int*)d_in[1];    // [B,L]
  const float* w_cls  = (const float*)d_in[2];  // [D,K]
  const float* b_cls  = (const float*)d_in[3];  // [K]
  const float* w_pool = (const float*)d_in[4];  // [D,D]
  const float* b_pool = (const float*)d_in[5];  // [D]
  const float* w_apc  = (const float*)d_in[6];  // [D,P]
  const float* b_apc  = (const float*)d_in[7];  // [P]

  float* out     = (float*)d_out;
  float* out_apc = out + (size_t)B_ * L_ * K_;

  int*   srcidx = (int*)d_ws;
  float* wt     = (float*)((char*)d_ws + WS_SRCIDX_BYTES);

  k1_prefix<<<B_, L_, 0, stream>>>(valid, w_cls, b_apc, srcidx, wt, out_apc);
  k2_fused<<<POOL_BLOCKS + ATE_BLOCKS, 256, 0, stream>>>(
      x, wt, b_cls, srcidx, w_pool, b_pool, w_apc, out, out_apc);
}